// Round 2
// baseline (260.810 us; speedup 1.0000x reference)
//
#include <hip/hip_runtime.h>
#include <math.h>

#define NA 360
#define NP 512
#define NB 16
#define IMG 512

typedef unsigned int uint32;

// RNE f32 -> bf16 (matches hardware cvt for non-NaN inputs)
static __device__ __forceinline__ unsigned short f2bf(float f) {
    union { float f; unsigned u; } v; v.f = f;
    unsigned u = v.u;
    return (unsigned short)((u + 0x7fffu + ((u >> 16) & 1u)) >> 16);
}
static __device__ __forceinline__ float bflo(uint32 u) {
    union { unsigned u; float f; } v; v.u = u << 16; return v.f;
}
static __device__ __forceinline__ float bfhi(uint32 u) {
    union { unsigned u; float f; } v; v.u = u & 0xffff0000u; return v.f;
}

// Per-angle table: {cos/dp, sin/dp, -pos0/dp, 0} so fidx = xs*ca + ys*sa + off
__global__ void prep_tab(const float* __restrict__ thetas,
                         const float* __restrict__ positions,
                         float4* __restrict__ tab) {
    int a = blockIdx.x * blockDim.x + threadIdx.x;
    if (a < NA) {
        double th = (double)thetas[a];
        double p0 = (double)positions[0];
        double dp = (double)positions[1] - p0;
        tab[a] = make_float4((float)(cos(th) / dp),
                             (float)(sin(th) / dp),
                             (float)(-p0 / dp), 0.0f);
    }
}

// [b][a][p] f32  ->  [a][p][b] bf16 (packed pairs in dwords, 32B per (a,p))
__global__ void transpose_cvt(const float* __restrict__ sino,
                              uint32* __restrict__ st) {
    int idx = blockIdx.x * 256 + threadIdx.x;  // idx = a*NP + p
    if (idx >= NA * NP) return;
    uint32 r[8];
#pragma unroll
    for (int k = 0; k < 8; ++k) {
        float a0 = sino[(size_t)(2 * k) * (NA * NP) + idx];
        float a1 = sino[(size_t)(2 * k + 1) * (NA * NP) + idx];
        r[k] = (uint32)f2bf(a0) | ((uint32)f2bf(a1) << 16);
    }
    uint4* dst = (uint4*)(st + (size_t)idx * 8);
    dst[0] = make_uint4(r[0], r[1], r[2], r[3]);
    dst[1] = make_uint4(r[4], r[5], r[6], r[7]);
}

// One thread = one (x,y) pixel, all 16 batches accumulated in registers.
__launch_bounds__(256)
__global__ void backproject(const uint32* __restrict__ st,
                            const float4* __restrict__ tab,
                            float* __restrict__ out) {
    const int x = blockIdx.x * 64 + threadIdx.x;
    const int y = blockIdx.y * 4 + threadIdx.y;
    const float xs = (float)x - ((IMG - 1) * 0.5f);
    const float ys = (float)y - ((IMG - 1) * 0.5f);
    float acc[NB];
#pragma unroll
    for (int b = 0; b < NB; ++b) acc[b] = 0.0f;

#pragma unroll 2
    for (int a = 0; a < NA; ++a) {
        const float4 t = tab[a];                 // uniform -> s_load
        const float fidx = fmaf(xs, t.x, fmaf(ys, t.y, t.z));
        const float fl = floorf(fidx);
        const float w = fidx - fl;
        const int i0 = (int)fl;
        const int i1 = i0 + 1;
        const float w0 = (i0 >= 0 && i0 < NP) ? (1.0f - w) : 0.0f;
        const float w1 = (i1 >= 0 && i1 < NP) ? w : 0.0f;
        const int i0c = min(max(i0, 0), NP - 1);
        const int i1c = min(max(i1, 0), NP - 1);
        const int rowbase = a * NP;
        const uint4* r0 = (const uint4*)(st + ((size_t)(rowbase + i0c) << 3));
        const uint4* r1 = (const uint4*)(st + ((size_t)(rowbase + i1c) << 3));
        const uint4 g0a = r0[0];
        const uint4 g0b = r0[1];
        const uint4 g1a = r1[0];
        const uint4 g1b = r1[1];
        const uint32 u0[8] = {g0a.x, g0a.y, g0a.z, g0a.w, g0b.x, g0b.y, g0b.z, g0b.w};
        const uint32 u1[8] = {g1a.x, g1a.y, g1a.z, g1a.w, g1b.x, g1b.y, g1b.z, g1b.w};
#pragma unroll
        for (int k = 0; k < 8; ++k) {
            acc[2 * k]     = fmaf(w0, bflo(u0[k]), fmaf(w1, bflo(u1[k]), acc[2 * k]));
            acc[2 * k + 1] = fmaf(w0, bfhi(u0[k]), fmaf(w1, bfhi(u1[k]), acc[2 * k + 1]));
        }
    }

    const size_t pix = (size_t)y * IMG + x;
#pragma unroll
    for (int b = 0; b < NB; ++b) {
        out[(size_t)b * (IMG * IMG) + pix] = acc[b];
    }
}

extern "C" void kernel_launch(void* const* d_in, const int* in_sizes, int n_in,
                              void* d_out, int out_size, void* d_ws, size_t ws_size,
                              hipStream_t stream) {
    const float* sino      = (const float*)d_in[0];
    const float* thetas    = (const float*)d_in[1];
    const float* positions = (const float*)d_in[2];
    float* out = (float*)d_out;

    float4* tab = (float4*)d_ws;                       // 360 * 16B
    uint32* st  = (uint32*)((char*)d_ws + 8192);       // 360*512*16 bf16 = 5.9MB

    prep_tab<<<dim3((NA + 63) / 64), dim3(64), 0, stream>>>(thetas, positions, tab);
    transpose_cvt<<<dim3((NA * NP) / 256), dim3(256), 0, stream>>>(sino, st);
    backproject<<<dim3(IMG / 64, IMG / 4), dim3(64, 4), 0, stream>>>(st, tab, out);
}